// Round 11
// baseline (177.766 us; speedup 1.0000x reference)
//
#include <hip/hip_runtime.h>

typedef __bf16 bf16_t;
typedef __bf16 bf16x8 __attribute__((ext_vector_type(8)));
typedef __bf16 bf16x4 __attribute__((ext_vector_type(4)));
typedef float  f32x4  __attribute__((ext_vector_type(4)));

#if __has_builtin(__builtin_amdgcn_exp2f)
#define EXP2(x) __builtin_amdgcn_exp2f(x)
#else
#define EXP2(x) exp2f(x)
#endif

#define DEVFN __device__ __forceinline__

DEVFN void gl_lds16(void* lds_base, const void* gsrc) {
  __builtin_amdgcn_global_load_lds(
      (const __attribute__((address_space(1))) void*)gsrc,
      (__attribute__((address_space(3))) void*)lds_base, 16, 0, 0);
}

// ---------------------------------------------------------------- prep:
// weight transposes (bid<1152) + q/k/v f32->bf16 converts (+ Vsum zero)
__global__ __launch_bounds__(256) void k_prep(
    const float* __restrict__ q, const float* __restrict__ k, const float* __restrict__ v,
    const float* __restrict__ w_qs, const float* __restrict__ w_ks,
    const float* __restrict__ w_vs, const float* __restrict__ fc_w,
    const float* __restrict__ resid_w,
    bf16_t* __restrict__ qb, bf16_t* __restrict__ kb, bf16_t* __restrict__ vb,
    bf16_t* __restrict__ wqsT, bf16_t* __restrict__ wksT, bf16_t* __restrict__ wvsT,
    bf16_t* __restrict__ fcwT, bf16_t* __restrict__ rswT,
    float* __restrict__ Vs) {
  __shared__ float t[64][65];
  int bid = blockIdx.x;
  if (bid < 1152) {
    const float* w; bf16_t* wt; int K;
    if (bid < 192)      { w = w_qs;    wt = wqsT; K = 768; }
    else if (bid < 448) { w = w_ks;    wt = wksT; K = 1024; bid -= 192; }
    else if (bid < 704) { w = w_vs;    wt = wvsT; K = 1024; bid -= 448; }
    else if (bid < 960) { w = fc_w;    wt = fcwT; K = 1024; bid -= 704; }
    else                { w = resid_w; wt = rswT; K = 768;  bid -= 960; }
    const int bk = (bid >> 4) << 6;
    const int bn = (bid & 15) << 6;
    const int rr = threadIdx.x >> 4;
    const int cc = (threadIdx.x & 15) << 2;
#pragma unroll
    for (int i = 0; i < 4; ++i) {
      int r = i * 16 + rr;
      float4 vv = *reinterpret_cast<const float4*>(&w[(size_t)(bk + r) * 1024 + bn + cc]);
      t[r][cc] = vv.x; t[r][cc + 1] = vv.y; t[r][cc + 2] = vv.z; t[r][cc + 3] = vv.w;
    }
    __syncthreads();
#pragma unroll
    for (int i = 0; i < 4; ++i) {
      int n = i * 16 + rr;
      bf16x4 o;
      o[0] = (bf16_t)t[cc][n];     o[1] = (bf16_t)t[cc + 1][n];
      o[2] = (bf16_t)t[cc + 2][n]; o[3] = (bf16_t)t[cc + 3][n];
      *reinterpret_cast<bf16x4*>(&wt[(size_t)(bn + n) * K + bk + cc]) = o;
    }
    return;
  }
  bid -= 1152;
  if (bid == 0) {
    for (int j = threadIdx.x; j < 8192; j += 256) Vs[j] = 0.f;  // atomic target
  }
  const int NQ = 1572864, NK = 2097152, NT = NQ + 2 * NK;
  int stride = (gridDim.x - 1152) * 256;
  for (int i = bid * 256 + threadIdx.x; i < NT; i += stride) {
    const float* src; bf16_t* dst; int off;
    if (i < NQ)           { src = q; dst = qb; off = i; }
    else if (i < NQ + NK) { src = k; dst = kb; off = i - NQ; }
    else                  { src = v; dst = vb; off = i - NQ - NK; }
    float4 vv = reinterpret_cast<const float4*>(src)[off];
    bf16x4 o;
    o[0] = (bf16_t)vv.x; o[1] = (bf16_t)vv.y; o[2] = (bf16_t)vv.z; o[3] = (bf16_t)vv.w;
    reinterpret_cast<bf16x4*>(dst)[off] = o;
  }
}

// ---------------------------------------------------------------- GEMM tile compute (double-buffered)
// LDS chunk-swizzle: chunk c of 64B-row r stored at c^((r>>1)&3).
// Read chunk lk^((lr>>1)&3): each (row-parity, chunk) pair gets exactly 2
// lanes -> 2-way, which folds into the inherent 2 port-cycles (free).
DEVFN void gemm_tiles(const bf16_t* __restrict__ A, const bf16_t* __restrict__ Bt,
                      int K, int m0, int n0, bf16_t (*sm)[4096], f32x4 (&acc)[4][4]) {
  const int lane = threadIdx.x & 63;
  const int wv = threadIdx.x >> 6;
  const int wr = (wv >> 1) * 64, wc = (wv & 1) * 64;
  const int lr = lane & 15, lk = lane >> 4;
  const int so0 = wv * 2048 + lane * 16;
  const int so1 = so0 + 1024;
  const int r0 = so0 >> 6, r1 = so1 >> 6;
  const int c0 = ((((so0 >> 4) & 3) ^ ((r0 >> 1) & 3)) << 4);
  const int c1 = ((((so1 >> 4) & 3) ^ ((r1 >> 1) & 3)) << 4);
  const int asw = ((lk ^ ((lr >> 1) & 3)) << 4);
  const char* Apc = (const char*)A;
  const char* Btc = (const char*)Bt;
  f32x4 zro = {0.f, 0.f, 0.f, 0.f};
#pragma unroll
  for (int i = 0; i < 4; ++i)
#pragma unroll
    for (int j = 0; j < 4; ++j) acc[i][j] = zro;

  const int nk = K >> 5;
  auto stage = [&](int buf, int t) {
    gl_lds16((char*)sm[buf] + wv * 2048,        Apc + ((size_t)(m0 + r0) * K + t * 32) * 2 + c0);
    gl_lds16((char*)sm[buf] + wv * 2048 + 1024, Apc + ((size_t)(m0 + r1) * K + t * 32) * 2 + c1);
    gl_lds16((char*)sm[2 + buf] + wv * 2048,        Btc + ((size_t)(n0 + r0) * K + t * 32) * 2 + c0);
    gl_lds16((char*)sm[2 + buf] + wv * 2048 + 1024, Btc + ((size_t)(n0 + r1) * K + t * 32) * 2 + c1);
  };
  stage(0, 0);
  __syncthreads();
  for (int t = 0; t < nk; ++t) {
    const int cur = t & 1;
    if (t + 1 < nk) stage(cur ^ 1, t + 1);
    const char* AsB = (const char*)sm[cur];
    const char* BsB = (const char*)sm[2 + cur];
    bf16x8 af[4], bfr[4];
#pragma unroll
    for (int i = 0; i < 4; ++i)
      af[i] = *(const bf16x8*)(AsB + (wr + i * 16 + lr) * 64 + asw);
#pragma unroll
    for (int j = 0; j < 4; ++j)
      bfr[j] = *(const bf16x8*)(BsB + (wc + j * 16 + lr) * 64 + asw);
#pragma unroll
    for (int i = 0; i < 4; ++i)
#pragma unroll
      for (int j = 0; j < 4; ++j)
        acc[i][j] = __builtin_amdgcn_mfma_f32_16x16x32_bf16(af[i], bfr[j], acc[i][j], 0, 0, 0);
    __syncthreads();
  }
}

// fused Q/K/V projections: 1536 blocks, 512 per projection.
// Route 0 = V (slowest: fused transpose epilogue) so its blocks dispatch first.
__global__ __launch_bounds__(256) void k_gemm_proj(
    const bf16_t* __restrict__ qb, const bf16_t* __restrict__ wqsT, bf16_t* __restrict__ Qp,
    const bf16_t* __restrict__ kb, const bf16_t* __restrict__ wksT, bf16_t* __restrict__ Kp,
    const bf16_t* __restrict__ vb, const bf16_t* __restrict__ wvsT, bf16_t* __restrict__ Vt,
    float* __restrict__ Vsum, float qscale) {
  __shared__ bf16_t sm[4][4096];
  const int bid = blockIdx.x;
  const int route = bid >> 9;          // 0:V 1:K 2:Q
  const int sbid = bid & 511;
  const int wg = (sbid & 7) * 64 + (sbid >> 3);   // XCD-grouped
  const int tn = 8;                                // N=1024 → 8 col tiles
  const int m0 = (wg / tn) << 7;
  const int n0 = (wg % tn) << 7;
  const int lane = threadIdx.x & 63;
  const int wv = threadIdx.x >> 6;
  const int wr = (wv >> 1) * 64, wc = (wv & 1) * 64;
  const int lr = lane & 15, lk = lane >> 4;
  f32x4 acc[4][4];

  if (route == 0) {
    gemm_tiles(vb, wvsT, 1024, m0, n0, sm, acc);
    // acc[i][j][r] = Vproj[kv = m0+wr+i*16+lk*4+r][n = n0+wc+j*16+lr]
    const int b = m0 >> 10;
    const int h0 = n0 >> 6;
    const int kt0 = (m0 & 1023) >> 6;
    const int h_local = wc >> 6, kt_local = wr >> 6;   // wave-constant
    char* tl = (char*)sm + (h_local * 2 + kt_local) * 8192;  // wave-private tile
#pragma unroll
    for (int i = 0; i < 4; ++i) {
      const int kvl = i * 16 + lk * 4;
      const int csel = kvl >> 3;
      const int hoff = (kvl & 7) * 2;
#pragma unroll
      for (int j = 0; j < 4; ++j) {
        const int d = j * 16 + lr;
        bf16x4 pw;
#pragma unroll
        for (int r = 0; r < 4; ++r) pw[r] = (bf16_t)acc[i][j][r];
        *reinterpret_cast<bf16x4*>(tl + d * 128 + ((csel ^ (d & 7)) << 4) + hoff) = pw;
      }
    }
    {
      const size_t gbase = (size_t)(b * 16 + h0 + h_local) * 131072 +
                           (size_t)(kt0 + kt_local) * 8192;
#pragma unroll
      for (int it = 0; it < 8; ++it)
        *reinterpret_cast<uint4*>((char*)Vt + gbase + it * 1024 + lane * 16) =
            *reinterpret_cast<const uint4*>(tl + it * 1024 + lane * 16);
    }
    const int h = h0 + h_local;
#pragma unroll
    for (int j = 0; j < 4; ++j) {
      float s = 0.f;
#pragma unroll
      for (int i = 0; i < 4; ++i)
#pragma unroll
        for (int r = 0; r < 4; ++r) s += acc[i][j][r];
      s += __shfl_xor(s, 16, 64);
      s += __shfl_xor(s, 32, 64);
      if (lane < 16)
        atomicAdd(&Vsum[(b * 16 + h) * 64 + j * 16 + lane], s);
    }
  } else if (route == 1) {
    gemm_tiles(kb, wksT, 1024, m0, n0, sm, acc);
#pragma unroll
    for (int i = 0; i < 4; ++i)
#pragma unroll
      for (int j = 0; j < 4; ++j)
#pragma unroll
        for (int r = 0; r < 4; ++r)
          Kp[(size_t)(m0 + wr + i * 16 + lk * 4 + r) * 1024 + n0 + wc + j * 16 + lr] =
              (bf16_t)acc[i][j][r];
  } else {
    gemm_tiles(qb, wqsT, 768, m0, n0, sm, acc);
#pragma unroll
    for (int i = 0; i < 4; ++i)
#pragma unroll
      for (int j = 0; j < 4; ++j)
#pragma unroll
        for (int r = 0; r < 4; ++r)
          Qp[(size_t)(m0 + wr + i * 16 + lk * 4 + r) * 1024 + n0 + wc + j * 16 + lr] =
              (bf16_t)(acc[i][j][r] * qscale);
  }
}

// Y[M,N] bf16 = A1*B1t^T + A2*B2t^T + bias — one continuous K-loop over both
// phases (stage pointers switch at nk1; acc accumulates across, sum is additive)
__global__ __launch_bounds__(256) void k_gemm_final(
    const bf16_t* __restrict__ A1, const bf16_t* __restrict__ B1t, int K1,
    const bf16_t* __restrict__ A2, const bf16_t* __restrict__ B2t, int K2,
    const float* __restrict__ bias, bf16_t* __restrict__ Y, int N) {
  __shared__ bf16_t sm[4][4096];
  const int bpx = gridDim.x >> 3;
  const int wg = (blockIdx.x & 7) * bpx + (blockIdx.x >> 3);
  const int tn = N >> 7;
  const int m0 = (wg / tn) << 7;
  const int n0 = (wg % tn) << 7;
  const int lane = threadIdx.x & 63;
  const int wv = threadIdx.x >> 6;
  const int wr = (wv >> 1) * 64, wc = (wv & 1) * 64;
  const int lr = lane & 15, lk = lane >> 4;
  const int so0 = wv * 2048 + lane * 16;
  const int so1 = so0 + 1024;
  const int r0 = so0 >> 6, r1 = so1 >> 6;
  const int c0 = ((((so0 >> 4) & 3) ^ ((r0 >> 1) & 3)) << 4);
  const int c1 = ((((so1 >> 4) & 3) ^ ((r1 >> 1) & 3)) << 4);
  const int asw = ((lk ^ ((lr >> 1) & 3)) << 4);
  f32x4 zro = {0.f, 0.f, 0.f, 0.f};
  f32x4 acc[4][4];
#pragma unroll
  for (int i = 0; i < 4; ++i)
#pragma unroll
    for (int j = 0; j < 4; ++j) acc[i][j] = zro;

  const int nk1 = K1 >> 5;
  const int nkt = (K1 + K2) >> 5;
  auto stage = [&](int buf, int t) {
    const char* Apc; const char* Btc; int K, tt;
    if (t < nk1) { Apc = (const char*)A1; Btc = (const char*)B1t; K = K1; tt = t; }
    else         { Apc = (const char*)A2; Btc = (const char*)B2t; K = K2; tt = t - nk1; }
    gl_lds16((char*)sm[buf] + wv * 2048,        Apc + ((size_t)(m0 + r0) * K + tt * 32) * 2 + c0);
    gl_lds16((char*)sm[buf] + wv * 2048 + 1024, Apc + ((size_t)(m0 + r1) * K + tt * 32) * 2 + c1);
    gl_lds16((char*)sm[2 + buf] + wv * 2048,        Btc + ((size_t)(n0 + r0) * K + tt * 32) * 2 + c0);
    gl_lds16((char*)sm[2 + buf] + wv * 2048 + 1024, Btc + ((size_t)(n0 + r1) * K + tt * 32) * 2 + c1);
  };
  stage(0, 0);
  __syncthreads();
  for (int t = 0; t < nkt; ++t) {
    const int cur = t & 1;
    if (t + 1 < nkt) stage(cur ^ 1, t + 1);
    const char* AsB = (const char*)sm[cur];
    const char* BsB = (const char*)sm[2 + cur];
    bf16x8 af[4], bfr[4];
#pragma unroll
    for (int i = 0; i < 4; ++i)
      af[i] = *(const bf16x8*)(AsB + (wr + i * 16 + lr) * 64 + asw);
#pragma unroll
    for (int j = 0; j < 4; ++j)
      bfr[j] = *(const bf16x8*)(BsB + (wc + j * 16 + lr) * 64 + asw);
#pragma unroll
    for (int i = 0; i < 4; ++i)
#pragma unroll
      for (int j = 0; j < 4; ++j)
        acc[i][j] = __builtin_amdgcn_mfma_f32_16x16x32_bf16(af[i], bfr[j], acc[i][j], 0, 0, 0);
    __syncthreads();
  }
#pragma unroll
  for (int i = 0; i < 4; ++i)
#pragma unroll
    for (int j = 0; j < 4; ++j) {
      float bv = bias[n0 + wc + j * 16 + lr];
#pragma unroll
      for (int r = 0; r < 4; ++r)
        Y[(size_t)(m0 + wr + i * 16 + lk * 4 + r) * N + n0 + wc + j * 16 + lr] =
            (bf16_t)(acc[i][j][r] + bv);
    }
}

// ---------------------------------------------------------------- attention
// QBLK=512, 1024 threads (16 waves). Wave w handles subtiles {2*(w>>2), +1};
// 4 waves per subtile pair (wrow = (w&3)*16). One K/V staging + one barrier
// per kt serves 512 q-rows; threads 0-511 stage K, 512-1023 stage V.
// Grid = 256 blocks = exactly 1 per CU (zero tail).
__global__ __launch_bounds__(1024) void k_attn(
    const bf16_t* __restrict__ Qp, const bf16_t* __restrict__ Kp,
    const bf16_t* __restrict__ Vt, const float* __restrict__ Vsum,
    bf16_t* __restrict__ Aout) {
  const int bid = blockIdx.x;
  const int wgid = (bid & 7) * 32 + (bid >> 3);   // XCD-grouping, 256 blocks
  const int qg = wgid & 1;                         // 512-row q-group
  const int bh = wgid >> 1;
  const int b = bh >> 4, h = bh & 15;
  __shared__ bf16_t Ks[2][4096];
  __shared__ bf16_t Vs[2][4096];
  const int tid = threadIdx.x;
  const int lane = tid & 63;
  const int wv = tid >> 6;            // 0..15
  const int lr = lane & 15, lk = lane >> 4;
  const int stb = (wv >> 2) * 2;      // subtile pair base: 0,2,4,6
  const int wrow = (wv & 3) * 16;

  const int o = (tid & 511) * 16;     // staging offset within 8KB tile
  const int row = o >> 7;
  const int sc = ((((o >> 4) & 7) ^ (row & 7)) << 4);
  const int srow = (row & 0x23) | ((row & 0x0C) << 1) | ((row & 0x10) >> 2);
  const bool isK = tid < 512;         // wave-uniform

  const char* Ksrc  = (const char*)(Kp + ((size_t)(b * 1024 + srow)) * 1024 + h * 64) + sc;
  const char* Vtile = (const char*)Vt + (size_t)bh * 131072 + o;
  const char* gsrc   = isK ? Ksrc : Vtile;
  const size_t gstep = isK ? (size_t)131072 : (size_t)8192;
  char* l0 = isK ? ((char*)&Ks[0][0] + o) : ((char*)&Vs[0][0] + o);
  char* l1 = isK ? ((char*)&Ks[1][0] + o) : ((char*)&Vs[1][0] + o);

  gl_lds16(l0, gsrc);

  bf16x8 qa[2][2];
#pragma unroll
  for (int stl = 0; stl < 2; ++stl) {
    const char* qsrc = (const char*)(Qp +
        ((size_t)(b * 1024 + qg * 512 + (stb + stl) * 64 + wrow + lr)) * 1024 + h * 64);
    qa[stl][0] = *(const bf16x8*)(qsrc + lk * 16);
    qa[stl][1] = *(const bf16x8*)(qsrc + 64 + lk * 16);
  }
  __syncthreads();

  const int kb0 = lr * 128 + ((lk ^ (lr & 7)) << 4);
  const int kb1 = lr * 128 + (((4 + lk) ^ (lr & 7)) << 4);

  f32x4 zro = {0.f, 0.f, 0.f, 0.f};
  f32x4 oacc[2][4];
  f32x4 sum[2];
#pragma unroll
  for (int stl = 0; stl < 2; ++stl) {
    sum[stl] = zro;
#pragma unroll
    for (int g = 0; g < 4; ++g) oacc[stl][g] = zro;
  }
  bf16x8 ones8;
#pragma unroll
  for (int j = 0; j < 8; ++j) ones8[j] = (bf16_t)1.0f;

  for (int kt = 0; kt < 16; ++kt) {
    const int cur = kt & 1;
    const char* KsB = (const char*)&Ks[cur][0];
    const char* VsB = (const char*)&Vs[cur][0];
    if (kt < 15)
      gl_lds16(cur ? l0 : l1, gsrc + (size_t)(kt + 1) * gstep);

    f32x4 sacc[2][4];
#pragma unroll
    for (int stl = 0; stl < 2; ++stl)
#pragma unroll
      for (int g = 0; g < 4; ++g) sacc[stl][g] = zro;
    {
      bf16x8 kf[4];
#pragma unroll
      for (int g = 0; g < 4; ++g) kf[g] = *(const bf16x8*)(KsB + kb0 + g * 2048);
#pragma unroll
      for (int stl = 0; stl < 2; ++stl)
#pragma unroll
        for (int g = 0; g < 4; ++g)
          sacc[stl][g] = __builtin_amdgcn_mfma_f32_16x16x32_bf16(kf[g], qa[stl][0], sacc[stl][g], 0, 0, 0);
#pragma unroll
      for (int g = 0; g < 4; ++g) kf[g] = *(const bf16x8*)(KsB + kb1 + g * 2048);
#pragma unroll
      for (int stl = 0; stl < 2; ++stl)
#pragma unroll
        for (int g = 0; g < 4; ++g)
          sacc[stl][g] = __builtin_amdgcn_mfma_f32_16x16x32_bf16(kf[g], qa[stl][1], sacc[stl][g], 0, 0, 0);
    }

    bf16x8 pa[2][2];
#pragma unroll
    for (int stl = 0; stl < 2; ++stl)
#pragma unroll
      for (int c = 0; c < 2; ++c) {
        bf16x8 pw;
#pragma unroll
        for (int r = 0; r < 4; ++r) {
          pw[r]     = (bf16_t)EXP2(sacc[stl][2 * c][r]);
          pw[4 + r] = (bf16_t)EXP2(sacc[stl][2 * c + 1][r]);
        }
        pa[stl][c] = pw;
      }

#pragma unroll
    for (int c = 0; c < 2; ++c) {
      const int vb = (c == 0) ? kb0 : kb1;
      bf16x8 vf[4];
#pragma unroll
      for (int gd = 0; gd < 4; ++gd)
        vf[gd] = *(const bf16x8*)(VsB + vb + gd * 2048);
#pragma unroll
      for (int stl = 0; stl < 2; ++stl) {
        sum[stl] = __builtin_amdgcn_mfma_f32_16x16x32_bf16(pa[stl][c], ones8, sum[stl], 0, 0, 0);
#pragma unroll
        for (int gd = 0; gd < 4; ++gd)
          oacc[stl][gd] = __builtin_amdgcn_mfma_f32_16x16x32_bf16(pa[stl][c], vf[gd], oacc[stl][gd], 0, 0, 0);
      }
    }
    __syncthreads();
  }

  float vs_d[4];
#pragma unroll
  for (int gd = 0; gd < 4; ++gd) vs_d[gd] = Vsum[bh * 64 + gd * 16 + lr];
#pragma unroll
  for (int stl = 0; stl < 2; ++stl) {
    float inv[4];
#pragma unroll
    for (int r = 0; r < 4; ++r) inv[r] = 1.0f / sum[stl][r];
#pragma unroll
    for (int gd = 0; gd < 4; ++gd)
#pragma unroll
      for (int r = 0; r < 4; ++r) {
        int d = gd * 16 + lr;
        int qrow = qg * 512 + (stb + stl) * 64 + wrow + lk * 4 + r;
        float attnv = oacc[stl][gd][r] * inv[r];
        float val = (vs_d[gd] - attnv) * (1.0f / 1023.0f);
        Aout[((size_t)(b * 1024 + qrow)) * 1024 + h * 64 + d] = (bf16_t)val;
      }
  }
}

// ---------------------------------------------------------------- layernorm (bf16 input)
__global__ __launch_bounds__(256) void k_ln(
    const bf16_t* __restrict__ Y, const float* __restrict__ gamma,
    const float* __restrict__ beta, float* __restrict__ out) {
  const int row = blockIdx.x, tid = threadIdx.x;
  bf16x4 xv = reinterpret_cast<const bf16x4*>(Y + (size_t)row * 1024)[tid];
  float x0 = (float)xv[0], x1 = (float)xv[1], x2 = (float)xv[2], x3 = (float)xv[3];
  float s = x0 + x1 + x2 + x3;
  float q = x0 * x0 + x1 * x1 + x2 * x2 + x3 * x3;
#pragma unroll
  for (int off = 32; off > 0; off >>= 1) {
    s += __shfl_xor(s, off, 64);
    q += __shfl_xor(q, off, 64);
  }
  __shared__ float ss[4], qs[4];
  if ((tid & 63) == 0) { ss[tid >> 6] = s; qs[tid >> 6] = q; }
  __syncthreads();
  s = ss[0] + ss[1] + ss[2] + ss[3];
  q = qs[0] + qs[1] + qs[2] + qs[3];
  float mean = s * (1.f / 1024.f);
  float var = q * (1.f / 1024.f) - mean * mean;
  float rstd = rsqrtf(var + 1e-5f);
  float4 g = reinterpret_cast<const float4*>(gamma)[tid];
  float4 bt = reinterpret_cast<const float4*>(beta)[tid];
  float4 o;
  o.x = (x0 - mean) * rstd * g.x + bt.x;
  o.y = (x1 - mean) * rstd * g.y + bt.y;
  o.z = (x2 - mean) * rstd * g.z + bt.z;
  o.w = (x3 - mean) * rstd * g.w + bt.w;
  reinterpret_cast<float4*>(out + (size_t)row * 1024)[tid] = o;
}

// ---------------------------------------------------------------- launch
extern "C" void kernel_launch(void* const* d_in, const int* in_sizes, int n_in,
                              void* d_out, int out_size, void* d_ws, size_t ws_size,
                              hipStream_t stream) {
  (void)in_sizes; (void)n_in; (void)out_size;
  const float* q       = (const float*)d_in[0];
  const float* k       = (const float*)d_in[1];
  const float* v       = (const float*)d_in[2];
  const float* w_qs    = (const float*)d_in[3];
  const float* w_ks    = (const float*)d_in[4];
  const float* w_vs    = (const float*)d_in[5];
  const float* fc_w    = (const float*)d_in[6];
  const float* resid_w = (const float*)d_in[7];
  const float* resid_b = (const float*)d_in[8];
  const float* ln_g    = (const float*)d_in[9];
  const float* ln_b    = (const float*)d_in[10];
  float* out = (float*)d_out;
  char* ws = (char*)d_ws;

  if (ws_size < (size_t)122716160) return;  // need ~117 MB

  bf16_t* qb   = (bf16_t*)(ws + 0);
  bf16_t* kb   = (bf16_t*)(ws + 12582912);
  bf16_t* vb   = (bf16_t*)(ws + 29360128);
  bf16_t* Y    = (bf16_t*)(ws + 12582912);  // aliases kb+vb (dead after projections)
  bf16_t* wqsT = (bf16_t*)(ws + 46137344);
  bf16_t* wksT = (bf16_t*)(ws + 47710208);
  bf16_t* wvsT = (bf16_t*)(ws + 49807360);
  bf16_t* fcwT = (bf16_t*)(ws + 51904512);
  bf16_t* rswT = (bf16_t*)(ws + 54001664);
  bf16_t* Qp   = (bf16_t*)(ws + 55574528);
  bf16_t* Kp   = (bf16_t*)(ws + 72351744);
  bf16_t* Aout = (bf16_t*)(ws + 89128960);
  bf16_t* VtT  = (bf16_t*)(ws + 105906176);
  float*  Vsm  = (float*)(ws + 122683392);

  k_prep<<<3200, 256, 0, stream>>>(q, k, v, w_qs, w_ks, w_vs, fc_w, resid_w,
                                   qb, kb, vb, wqsT, wksT, wvsT, fcwT, rswT, Vsm);
  // Q pre-scale: 1/8 * log2(e) so scores feed 2^x directly
  k_gemm_proj<<<1536, 256, 0, stream>>>(qb, wqsT, Qp, kb, wksT, Kp, vb, wvsT, VtT,
                                        Vsm, 0.18033688011f);
  k_attn<<<256, 1024, 0, stream>>>(Qp, Kp, VtT, Vsm, Aout);
  k_gemm_final<<<512, 256, 0, stream>>>(Aout, fcwT, 1024, qb, rswT, 768, resid_b, Y, 1024);
  k_ln<<<8192, 256, 0, stream>>>(Y, ln_g, ln_b, out);
}

// Round 12
// 167.930 us; speedup vs baseline: 1.0586x; 1.0586x over previous
//
#include <hip/hip_runtime.h>

typedef __bf16 bf16_t;
typedef __bf16 bf16x8 __attribute__((ext_vector_type(8)));
typedef __bf16 bf16x4 __attribute__((ext_vector_type(4)));
typedef float  f32x4  __attribute__((ext_vector_type(4)));

#if __has_builtin(__builtin_amdgcn_exp2f)
#define EXP2(x) __builtin_amdgcn_exp2f(x)
#else
#define EXP2(x) exp2f(x)
#endif

#define DEVFN __device__ __forceinline__

DEVFN void gl_lds16(void* lds_base, const void* gsrc) {
  __builtin_amdgcn_global_load_lds(
      (const __attribute__((address_space(1))) void*)gsrc,
      (__attribute__((address_space(3))) void*)lds_base, 16, 0, 0);
}

// ---------------------------------------------------------------- prep:
// weight transposes (bid<1152) + q/k/v f32->bf16 converts (+ Vsum zero)
__global__ __launch_bounds__(256) void k_prep(
    const float* __restrict__ q, const float* __restrict__ k, const float* __restrict__ v,
    const float* __restrict__ w_qs, const float* __restrict__ w_ks,
    const float* __restrict__ w_vs, const float* __restrict__ fc_w,
    const float* __restrict__ resid_w,
    bf16_t* __restrict__ qb, bf16_t* __restrict__ kb, bf16_t* __restrict__ vb,
    bf16_t* __restrict__ wqsT, bf16_t* __restrict__ wksT, bf16_t* __restrict__ wvsT,
    bf16_t* __restrict__ fcwT, bf16_t* __restrict__ rswT,
    float* __restrict__ Vs) {
  __shared__ float t[64][65];
  int bid = blockIdx.x;
  if (bid < 1152) {
    const float* w; bf16_t* wt; int K;
    if (bid < 192)      { w = w_qs;    wt = wqsT; K = 768; }
    else if (bid < 448) { w = w_ks;    wt = wksT; K = 1024; bid -= 192; }
    else if (bid < 704) { w = w_vs;    wt = wvsT; K = 1024; bid -= 448; }
    else if (bid < 960) { w = fc_w;    wt = fcwT; K = 1024; bid -= 704; }
    else                { w = resid_w; wt = rswT; K = 768;  bid -= 960; }
    const int bk = (bid >> 4) << 6;
    const int bn = (bid & 15) << 6;
    const int rr = threadIdx.x >> 4;
    const int cc = (threadIdx.x & 15) << 2;
#pragma unroll
    for (int i = 0; i < 4; ++i) {
      int r = i * 16 + rr;
      float4 vv = *reinterpret_cast<const float4*>(&w[(size_t)(bk + r) * 1024 + bn + cc]);
      t[r][cc] = vv.x; t[r][cc + 1] = vv.y; t[r][cc + 2] = vv.z; t[r][cc + 3] = vv.w;
    }
    __syncthreads();
#pragma unroll
    for (int i = 0; i < 4; ++i) {
      int n = i * 16 + rr;
      bf16x4 o;
      o[0] = (bf16_t)t[cc][n];     o[1] = (bf16_t)t[cc + 1][n];
      o[2] = (bf16_t)t[cc + 2][n]; o[3] = (bf16_t)t[cc + 3][n];
      *reinterpret_cast<bf16x4*>(&wt[(size_t)(bn + n) * K + bk + cc]) = o;
    }
    return;
  }
  bid -= 1152;
  if (bid == 0) {
    for (int j = threadIdx.x; j < 8192; j += 256) Vs[j] = 0.f;  // atomic target
  }
  const int NQ = 1572864, NK = 2097152, NT = NQ + 2 * NK;
  int stride = (gridDim.x - 1152) * 256;
  for (int i = bid * 256 + threadIdx.x; i < NT; i += stride) {
    const float* src; bf16_t* dst; int off;
    if (i < NQ)           { src = q; dst = qb; off = i; }
    else if (i < NQ + NK) { src = k; dst = kb; off = i - NQ; }
    else                  { src = v; dst = vb; off = i - NQ - NK; }
    float4 vv = reinterpret_cast<const float4*>(src)[off];
    bf16x4 o;
    o[0] = (bf16_t)vv.x; o[1] = (bf16_t)vv.y; o[2] = (bf16_t)vv.z; o[3] = (bf16_t)vv.w;
    reinterpret_cast<bf16x4*>(dst)[off] = o;
  }
}

// ---------------------------------------------------------------- GEMM tile compute
// 3-buffer 2-deep pipeline, counted vmcnt, raw barriers (no full drains in loop).
// sm = 6 x 8KB: buffer i uses sm[2i] (A) and sm[2i+1] (B).
DEVFN void gemm_tiles(const bf16_t* __restrict__ A, const bf16_t* __restrict__ Bt,
                      int K, int m0, int n0, bf16_t (*sm)[4096], f32x4 (&acc)[4][4]) {
  const int lane = threadIdx.x & 63;
  const int wv = threadIdx.x >> 6;
  const int wr = (wv >> 1) * 64, wc = (wv & 1) * 64;
  const int lr = lane & 15, lk = lane >> 4;
  const int so0 = wv * 2048 + lane * 16;
  const int so1 = so0 + 1024;
  const int r0 = so0 >> 6, r1 = so1 >> 6;
  const int c0 = ((((so0 >> 4) & 3) ^ ((r0 >> 1) & 3)) << 4);
  const int c1 = ((((so1 >> 4) & 3) ^ ((r1 >> 1) & 3)) << 4);
  const int asw = ((lk ^ ((lr >> 1) & 3)) << 4);
  const char* Apc = (const char*)A;
  const char* Btc = (const char*)Bt;
  f32x4 zro = {0.f, 0.f, 0.f, 0.f};
#pragma unroll
  for (int i = 0; i < 4; ++i)
#pragma unroll
    for (int j = 0; j < 4; ++j) acc[i][j] = zro;

  const int nk = K >> 5;
  auto stage = [&](int buf, int t) {
    gl_lds16((char*)sm[2 * buf]     + wv * 2048,        Apc + ((size_t)(m0 + r0) * K + t * 32) * 2 + c0);
    gl_lds16((char*)sm[2 * buf]     + wv * 2048 + 1024, Apc + ((size_t)(m0 + r1) * K + t * 32) * 2 + c1);
    gl_lds16((char*)sm[2 * buf + 1] + wv * 2048,        Btc + ((size_t)(n0 + r0) * K + t * 32) * 2 + c0);
    gl_lds16((char*)sm[2 * buf + 1] + wv * 2048 + 1024, Btc + ((size_t)(n0 + r1) * K + t * 32) * 2 + c1);
  };
  stage(0, 0);
  if (nk > 1) {
    stage(1, 1);
    asm volatile("s_waitcnt vmcnt(4)" ::: "memory");   // tile0 in LDS; tile1 in flight
  } else {
    asm volatile("s_waitcnt vmcnt(0)" ::: "memory");
  }
  __builtin_amdgcn_s_barrier();

  for (int t = 0; t < nk; ++t) {
    const int cur = t % 3;
    const char* AsB = (const char*)sm[2 * cur];
    const char* BsB = (const char*)sm[2 * cur + 1];
    bf16x8 af[4], bfr[4];
#pragma unroll
    for (int i = 0; i < 4; ++i)
      af[i] = *(const bf16x8*)(AsB + (wr + i * 16 + lr) * 64 + asw);
#pragma unroll
    for (int j = 0; j < 4; ++j)
      bfr[j] = *(const bf16x8*)(BsB + (wc + j * 16 + lr) * 64 + asw);
#pragma unroll
    for (int i = 0; i < 4; ++i)
#pragma unroll
      for (int j = 0; j < 4; ++j)
        acc[i][j] = __builtin_amdgcn_mfma_f32_16x16x32_bf16(af[i], bfr[j], acc[i][j], 0, 0, 0);
    // all ds_reads of buf[cur] completed (lgkm deps precede MFMA issue)
    __builtin_amdgcn_s_barrier();                       // block-wide: safe to overwrite buf[cur]
    if (t + 2 < nk) stage((t + 2) % 3, t + 2);          // prefetch 2 ahead into freed buffer
    if (t + 1 < nk) {
      if (t + 2 < nk) asm volatile("s_waitcnt vmcnt(4)" ::: "memory");  // t+1 done; t+2 in flight
      else            asm volatile("s_waitcnt vmcnt(0)" ::: "memory");
      __builtin_amdgcn_s_barrier();                     // publish tile t+1 to all waves
    }
  }
}

// fused Q/K/V projections: 1536 blocks, 512 per projection.
// Route 0 = V (slowest: fused transpose epilogue) so its blocks dispatch first.
__global__ __launch_bounds__(256, 3) void k_gemm_proj(
    const bf16_t* __restrict__ qb, const bf16_t* __restrict__ wqsT, bf16_t* __restrict__ Qp,
    const bf16_t* __restrict__ kb, const bf16_t* __restrict__ wksT, bf16_t* __restrict__ Kp,
    const bf16_t* __restrict__ vb, const bf16_t* __restrict__ wvsT, bf16_t* __restrict__ Vt,
    float* __restrict__ Vsum, float qscale) {
  __shared__ bf16_t sm[6][4096];   // 48KB: 3 pipeline buffers
  const int bid = blockIdx.x;
  const int route = bid >> 9;          // 0:V 1:K 2:Q
  const int sbid = bid & 511;
  const int wg = (sbid & 7) * 64 + (sbid >> 3);   // XCD-grouped
  const int tn = 8;                                // N=1024 → 8 col tiles
  const int m0 = (wg / tn) << 7;
  const int n0 = (wg % tn) << 7;
  const int lane = threadIdx.x & 63;
  const int wv = threadIdx.x >> 6;
  const int wr = (wv >> 1) * 64, wc = (wv & 1) * 64;
  const int lr = lane & 15, lk = lane >> 4;
  f32x4 acc[4][4];

  if (route == 0) {
    gemm_tiles(vb, wvsT, 1024, m0, n0, sm, acc);
    // acc[i][j][r] = Vproj[kv = m0+wr+i*16+lk*4+r][n = n0+wc+j*16+lr]
    const int b = m0 >> 10;
    const int h0 = n0 >> 6;
    const int kt0 = (m0 & 1023) >> 6;
    const int h_local = wc >> 6, kt_local = wr >> 6;   // wave-constant
    char* tl = (char*)sm + (h_local * 2 + kt_local) * 8192;  // wave-private tile
#pragma unroll
    for (int i = 0; i < 4; ++i) {
      const int kvl = i * 16 + lk * 4;
      const int csel = kvl >> 3;
      const int hoff = (kvl & 7) * 2;
#pragma unroll
      for (int j = 0; j < 4; ++j) {
        const int d = j * 16 + lr;
        bf16x4 pw;
#pragma unroll
        for (int r = 0; r < 4; ++r) pw[r] = (bf16_t)acc[i][j][r];
        *reinterpret_cast<bf16x4*>(tl + d * 128 + ((csel ^ (d & 7)) << 4) + hoff) = pw;
      }
    }
    {
      const size_t gbase = (size_t)(b * 16 + h0 + h_local) * 131072 +
                           (size_t)(kt0 + kt_local) * 8192;
#pragma unroll
      for (int it = 0; it < 8; ++it)
        *reinterpret_cast<uint4*>((char*)Vt + gbase + it * 1024 + lane * 16) =
            *reinterpret_cast<const uint4*>(tl + it * 1024 + lane * 16);
    }
    const int h = h0 + h_local;
#pragma unroll
    for (int j = 0; j < 4; ++j) {
      float s = 0.f;
#pragma unroll
      for (int i = 0; i < 4; ++i)
#pragma unroll
        for (int r = 0; r < 4; ++r) s += acc[i][j][r];
      s += __shfl_xor(s, 16, 64);
      s += __shfl_xor(s, 32, 64);
      if (lane < 16)
        atomicAdd(&Vsum[(b * 16 + h) * 64 + j * 16 + lane], s);
    }
  } else if (route == 1) {
    gemm_tiles(kb, wksT, 1024, m0, n0, sm, acc);
#pragma unroll
    for (int i = 0; i < 4; ++i)
#pragma unroll
      for (int j = 0; j < 4; ++j)
#pragma unroll
        for (int r = 0; r < 4; ++r)
          Kp[(size_t)(m0 + wr + i * 16 + lk * 4 + r) * 1024 + n0 + wc + j * 16 + lr] =
              (bf16_t)acc[i][j][r];
  } else {
    gemm_tiles(qb, wqsT, 768, m0, n0, sm, acc);
#pragma unroll
    for (int i = 0; i < 4; ++i)
#pragma unroll
      for (int j = 0; j < 4; ++j)
#pragma unroll
        for (int r = 0; r < 4; ++r)
          Qp[(size_t)(m0 + wr + i * 16 + lk * 4 + r) * 1024 + n0 + wc + j * 16 + lr] =
              (bf16_t)(acc[i][j][r] * qscale);
  }
}

// Y[M,N] bf16 = A1*B1t^T + A2*B2t^T + bias — one continuous K-loop over both
// phases, 3-buffer counted-vmcnt pipeline (same discipline as gemm_tiles).
__global__ __launch_bounds__(256, 3) void k_gemm_final(
    const bf16_t* __restrict__ A1, const bf16_t* __restrict__ B1t, int K1,
    const bf16_t* __restrict__ A2, const bf16_t* __restrict__ B2t, int K2,
    const float* __restrict__ bias, bf16_t* __restrict__ Y, int N) {
  __shared__ bf16_t sm[6][4096];
  const int bpx = gridDim.x >> 3;
  const int wg = (blockIdx.x & 7) * bpx + (blockIdx.x >> 3);
  const int tn = N >> 7;
  const int m0 = (wg / tn) << 7;
  const int n0 = (wg % tn) << 7;
  const int lane = threadIdx.x & 63;
  const int wv = threadIdx.x >> 6;
  const int wr = (wv >> 1) * 64, wc = (wv & 1) * 64;
  const int lr = lane & 15, lk = lane >> 4;
  const int so0 = wv * 2048 + lane * 16;
  const int so1 = so0 + 1024;
  const int r0 = so0 >> 6, r1 = so1 >> 6;
  const int c0 = ((((so0 >> 4) & 3) ^ ((r0 >> 1) & 3)) << 4);
  const int c1 = ((((so1 >> 4) & 3) ^ ((r1 >> 1) & 3)) << 4);
  const int asw = ((lk ^ ((lr >> 1) & 3)) << 4);
  f32x4 zro = {0.f, 0.f, 0.f, 0.f};
  f32x4 acc[4][4];
#pragma unroll
  for (int i = 0; i < 4; ++i)
#pragma unroll
    for (int j = 0; j < 4; ++j) acc[i][j] = zro;

  const int nk1 = K1 >> 5;
  const int nkt = (K1 + K2) >> 5;
  auto stage = [&](int buf, int t) {
    const char* Apc; const char* Btc; int K, tt;
    if (t < nk1) { Apc = (const char*)A1; Btc = (const char*)B1t; K = K1; tt = t; }
    else         { Apc = (const char*)A2; Btc = (const char*)B2t; K = K2; tt = t - nk1; }
    gl_lds16((char*)sm[2 * buf]     + wv * 2048,        Apc + ((size_t)(m0 + r0) * K + tt * 32) * 2 + c0);
    gl_lds16((char*)sm[2 * buf]     + wv * 2048 + 1024, Apc + ((size_t)(m0 + r1) * K + tt * 32) * 2 + c1);
    gl_lds16((char*)sm[2 * buf + 1] + wv * 2048,        Btc + ((size_t)(n0 + r0) * K + tt * 32) * 2 + c0);
    gl_lds16((char*)sm[2 * buf + 1] + wv * 2048 + 1024, Btc + ((size_t)(n0 + r1) * K + tt * 32) * 2 + c1);
  };
  stage(0, 0);
  stage(1, 1);
  asm volatile("s_waitcnt vmcnt(4)" ::: "memory");
  __builtin_amdgcn_s_barrier();
  for (int t = 0; t < nkt; ++t) {
    const int cur = t % 3;
    const char* AsB = (const char*)sm[2 * cur];
    const char* BsB = (const char*)sm[2 * cur + 1];
    bf16x8 af[4], bfr[4];
#pragma unroll
    for (int i = 0; i < 4; ++i)
      af[i] = *(const bf16x8*)(AsB + (wr + i * 16 + lr) * 64 + asw);
#pragma unroll
    for (int j = 0; j < 4; ++j)
      bfr[j] = *(const bf16x8*)(BsB + (wc + j * 16 + lr) * 64 + asw);
#pragma unroll
    for (int i = 0; i < 4; ++i)
#pragma unroll
      for (int j = 0; j < 4; ++j)
        acc[i][j] = __builtin_amdgcn_mfma_f32_16x16x32_bf16(af[i], bfr[j], acc[i][j], 0, 0, 0);
    __builtin_amdgcn_s_barrier();
    if (t + 2 < nkt) stage((t + 2) % 3, t + 2);
    if (t + 1 < nkt) {
      if (t + 2 < nkt) asm volatile("s_waitcnt vmcnt(4)" ::: "memory");
      else             asm volatile("s_waitcnt vmcnt(0)" ::: "memory");
      __builtin_amdgcn_s_barrier();
    }
  }
#pragma unroll
  for (int i = 0; i < 4; ++i)
#pragma unroll
    for (int j = 0; j < 4; ++j) {
      float bv = bias[n0 + wc + j * 16 + lr];
#pragma unroll
      for (int r = 0; r < 4; ++r)
        Y[(size_t)(m0 + wr + i * 16 + lk * 4 + r) * N + n0 + wc + j * 16 + lr] =
            (bf16_t)(acc[i][j][r] + bv);
    }
}

// ---------------------------------------------------------------- attention (unchanged from r11)
__global__ __launch_bounds__(1024) void k_attn(
    const bf16_t* __restrict__ Qp, const bf16_t* __restrict__ Kp,
    const bf16_t* __restrict__ Vt, const float* __restrict__ Vsum,
    bf16_t* __restrict__ Aout) {
  const int bid = blockIdx.x;
  const int wgid = (bid & 7) * 32 + (bid >> 3);   // XCD-grouping, 256 blocks
  const int qg = wgid & 1;                         // 512-row q-group
  const int bh = wgid >> 1;
  const int b = bh >> 4, h = bh & 15;
  __shared__ bf16_t Ks[2][4096];
  __shared__ bf16_t Vs[2][4096];
  const int tid = threadIdx.x;
  const int lane = tid & 63;
  const int wv = tid >> 6;            // 0..15
  const int lr = lane & 15, lk = lane >> 4;
  const int stb = (wv >> 2) * 2;      // subtile pair base: 0,2,4,6
  const int wrow = (wv & 3) * 16;

  const int o = (tid & 511) * 16;     // staging offset within 8KB tile
  const int row = o >> 7;
  const int sc = ((((o >> 4) & 7) ^ (row & 7)) << 4);
  const int srow = (row & 0x23) | ((row & 0x0C) << 1) | ((row & 0x10) >> 2);
  const bool isK = tid < 512;         // wave-uniform

  const char* Ksrc  = (const char*)(Kp + ((size_t)(b * 1024 + srow)) * 1024 + h * 64) + sc;
  const char* Vtile = (const char*)Vt + (size_t)bh * 131072 + o;
  const char* gsrc   = isK ? Ksrc : Vtile;
  const size_t gstep = isK ? (size_t)131072 : (size_t)8192;
  char* l0 = isK ? ((char*)&Ks[0][0] + o) : ((char*)&Vs[0][0] + o);
  char* l1 = isK ? ((char*)&Ks[1][0] + o) : ((char*)&Vs[1][0] + o);

  gl_lds16(l0, gsrc);

  bf16x8 qa[2][2];
#pragma unroll
  for (int stl = 0; stl < 2; ++stl) {
    const char* qsrc = (const char*)(Qp +
        ((size_t)(b * 1024 + qg * 512 + (stb + stl) * 64 + wrow + lr)) * 1024 + h * 64);
    qa[stl][0] = *(const bf16x8*)(qsrc + lk * 16);
    qa[stl][1] = *(const bf16x8*)(qsrc + 64 + lk * 16);
  }
  __syncthreads();

  const int kb0 = lr * 128 + ((lk ^ (lr & 7)) << 4);
  const int kb1 = lr * 128 + (((4 + lk) ^ (lr & 7)) << 4);

  f32x4 zro = {0.f, 0.f, 0.f, 0.f};
  f32x4 oacc[2][4];
  f32x4 sum[2];
#pragma unroll
  for (int stl = 0; stl < 2; ++stl) {
    sum[stl] = zro;
#pragma unroll
    for (int g = 0; g < 4; ++g) oacc[stl][g] = zro;
  }
  bf16x8 ones8;
#pragma unroll
  for (int j = 0; j < 8; ++j) ones8[j] = (bf16_t)1.0f;

  for (int kt = 0; kt < 16; ++kt) {
    const int cur = kt & 1;
    const char* KsB = (const char*)&Ks[cur][0];
    const char* VsB = (const char*)&Vs[cur][0];
    if (kt < 15)
      gl_lds16(cur ? l0 : l1, gsrc + (size_t)(kt + 1) * gstep);

    f32x4 sacc[2][4];
#pragma unroll
    for (int stl = 0; stl < 2; ++stl)
#pragma unroll
      for (int g = 0; g < 4; ++g) sacc[stl][g] = zro;
    {
      bf16x8 kf[4];
#pragma unroll
      for (int g = 0; g < 4; ++g) kf[g] = *(const bf16x8*)(KsB + kb0 + g * 2048);
#pragma unroll
      for (int stl = 0; stl < 2; ++stl)
#pragma unroll
        for (int g = 0; g < 4; ++g)
          sacc[stl][g] = __builtin_amdgcn_mfma_f32_16x16x32_bf16(kf[g], qa[stl][0], sacc[stl][g], 0, 0, 0);
#pragma unroll
      for (int g = 0; g < 4; ++g) kf[g] = *(const bf16x8*)(KsB + kb1 + g * 2048);
#pragma unroll
      for (int stl = 0; stl < 2; ++stl)
#pragma unroll
        for (int g = 0; g < 4; ++g)
          sacc[stl][g] = __builtin_amdgcn_mfma_f32_16x16x32_bf16(kf[g], qa[stl][1], sacc[stl][g], 0, 0, 0);
    }

    bf16x8 pa[2][2];
#pragma unroll
    for (int stl = 0; stl < 2; ++stl)
#pragma unroll
      for (int c = 0; c < 2; ++c) {
        bf16x8 pw;
#pragma unroll
        for (int r = 0; r < 4; ++r) {
          pw[r]     = (bf16_t)EXP2(sacc[stl][2 * c][r]);
          pw[4 + r] = (bf16_t)EXP2(sacc[stl][2 * c + 1][r]);
        }
        pa[stl][c] = pw;
      }

#pragma unroll
    for (int c = 0; c < 2; ++c) {
      const int vb = (c == 0) ? kb0 : kb1;
      bf16x8 vf[4];
#pragma unroll
      for (int gd = 0; gd < 4; ++gd)
        vf[gd] = *(const bf16x8*)(VsB + vb + gd * 2048);
#pragma unroll
      for (int stl = 0; stl < 2; ++stl) {
        sum[stl] = __builtin_amdgcn_mfma_f32_16x16x32_bf16(pa[stl][c], ones8, sum[stl], 0, 0, 0);
#pragma unroll
        for (int gd = 0; gd < 4; ++gd)
          oacc[stl][gd] = __builtin_amdgcn_mfma_f32_16x16x32_bf16(pa[stl][c], vf[gd], oacc[stl][gd], 0, 0, 0);
      }
    }
    __syncthreads();
  }

  float vs_d[4];
#pragma unroll
  for (int gd = 0; gd < 4; ++gd) vs_d[gd] = Vsum[bh * 64 + gd * 16 + lr];
#pragma unroll
  for (int stl = 0; stl < 2; ++stl) {
    float inv[4];
#pragma unroll
    for (int r = 0; r < 4; ++r) inv[r] = 1.0f / sum[stl][r];
#pragma unroll
    for (int gd = 0; gd < 4; ++gd)
#pragma unroll
      for (int r = 0; r < 4; ++r) {
        int d = gd * 16 + lr;
        int qrow = qg * 512 + (stb + stl) * 64 + wrow + lk * 4 + r;
        float attnv = oacc[stl][gd][r] * inv[r];
        float val = (vs_d[gd] - attnv) * (1.0f / 1023.0f);
        Aout[((size_t)(b * 1024 + qrow)) * 1024 + h * 64 + d] = (bf16_t)val;
      }
  }
}

// ---------------------------------------------------------------- layernorm (bf16 input)
__global__ __launch_bounds__(256) void k_ln(
    const bf16_t* __restrict__ Y, const float* __restrict__ gamma,
    const float* __restrict__ beta, float* __restrict__ out) {
  const int row = blockIdx.x, tid = threadIdx.x;
  bf16x4 xv = reinterpret_cast<const bf16x4*>(Y + (size_t)row * 1024)[tid];
  float x0 = (float)xv[0], x1 = (float)xv[1], x2 = (float)xv[2], x3 = (float)xv[3];
  float s = x0 + x1 + x2 + x3;
  float q = x0 * x0 + x1 * x1 + x2 * x2 + x3 * x3;
#pragma unroll
  for (int off = 32; off > 0; off >>= 1) {
    s += __shfl_xor(s, off, 64);
    q += __shfl_xor(q, off, 64);
  }
  __shared__ float ss[4], qs[4];
  if ((tid & 63) == 0) { ss[tid >> 6] = s; qs[tid >> 6] = q; }
  __syncthreads();
  s = ss[0] + ss[1] + ss[2] + ss[3];
  q = qs[0] + qs[1] + qs[2] + qs[3];
  float mean = s * (1.f / 1024.f);
  float var = q * (1.f / 1024.f) - mean * mean;
  float rstd = rsqrtf(var + 1e-5f);
  float4 g = reinterpret_cast<const float4*>(gamma)[tid];
  float4 bt = reinterpret_cast<const float4*>(beta)[tid];
  float4 o;
  o.x = (x0 - mean) * rstd * g.x + bt.x;
  o.y = (x1 - mean) * rstd * g.y + bt.y;
  o.z = (x2 - mean) * rstd * g.z + bt.z;
  o.w = (x3 - mean) * rstd * g.w + bt.w;
  reinterpret_cast<float4*>(out + (size_t)row * 1024)[tid] = o;
}

// ---------------------------------------------------------------- launch
extern "C" void kernel_launch(void* const* d_in, const int* in_sizes, int n_in,
                              void* d_out, int out_size, void* d_ws, size_t ws_size,
                              hipStream_t stream) {
  (void)in_sizes; (void)n_in; (void)out_size;
  const float* q       = (const float*)d_in[0];
  const float* k       = (const float*)d_in[1];
  const float* v       = (const float*)d_in[2];
  const float* w_qs    = (const float*)d_in[3];
  const float* w_ks    = (const float*)d_in[4];
  const float* w_vs    = (const float*)d_in[5];
  const float* fc_w    = (const float*)d_in[6];
  const float* resid_w = (const float*)d_in[7];
  const float* resid_b = (const float*)d_in[8];
  const float* ln_g    = (const float*)d_in[9];
  const float* ln_b    = (const float*)d_in[10];
  float* out = (float*)d_out;
  char* ws = (char*)d_ws;

  if (ws_size < (size_t)122716160) return;  // need ~117 MB

  bf16_t* qb   = (bf16_t*)(ws + 0);
  bf16_t* kb   = (bf16_t*)(ws + 12582912);
  bf16_t* vb   = (bf16_t*)(ws + 29360128);
  bf16_t* Y    = (bf16_t*)(ws + 12582912);  // aliases kb+vb (dead after projections)
  bf16_t* wqsT = (bf16_t*)(ws + 46137344);
  bf16_t* wksT = (bf16_t*)(ws + 47710208);
  bf16_t* wvsT = (bf16_t*)(ws + 49807360);
  bf16_t* fcwT = (bf16_t*)(ws + 51904512);
  bf16_t* rswT = (bf16_t*)(ws + 54001664);
  bf16_t* Qp   = (bf16_t*)(ws + 55574528);
  bf16_t* Kp   = (bf16_t*)(ws + 72351744);
  bf16_t* Aout = (bf16_t*)(ws + 89128960);
  bf16_t* VtT  = (bf16_t*)(ws + 105906176);
  float*  Vsm  = (float*)(ws + 122683392);

  k_prep<<<3200, 256, 0, stream>>>(q, k, v, w_qs, w_ks, w_vs, fc_w, resid_w,
                                   qb, kb, vb, wqsT, wksT, wvsT, fcwT, rswT, Vsm);
  // Q pre-scale: 1/8 * log2(e) so scores feed 2^x directly
  k_gemm_proj<<<1536, 256, 0, stream>>>(qb, wqsT, Qp, kb, wksT, Kp, vb, wvsT, VtT,
                                        Vsm, 0.18033688011f);
  k_attn<<<256, 1024, 0, stream>>>(Qp, Kp, VtT, Vsm, Aout);
  k_gemm_final<<<512, 256, 0, stream>>>(Aout, fcwT, 1024, qb, rswT, 768, resid_b, Y, 1024);
  k_ln<<<8192, 256, 0, stream>>>(Y, ln_g, ln_b, out);
}